// Round 3
// baseline (2289.846 us; speedup 1.0000x reference)
//
#include <hip/hip_runtime.h>
#include <hip/hip_bf16.h>

typedef __hip_bfloat16 bf16;
typedef short bf16x8 __attribute__((ext_vector_type(8)));
typedef float f32x4 __attribute__((ext_vector_type(4)));

#define BNS 0.9999950000374997f  /* 1/sqrt(1+1e-5) */

__device__ __forceinline__ float bf2f(bf16 v) { return __bfloat162float(v); }
__device__ __forceinline__ float geluf(float x) { return 0.5f * x * (1.0f + erff(x * 0.70710678118654752f)); }
__device__ __forceinline__ float sigmf(float x) { return 1.0f / (1.0f + expf(-x)); }
__device__ __forceinline__ unsigned short f2b(float f) { bf16 h = __float2bfloat16(f); return *(unsigned short*)&h; }

// ---------------- weight prep #1: PA folded + transposed, LA transposed+folded, fuse1^T -----
// W1F[k*64+j] = pa_w1[k][j]*g[k]*BNS            (16384)
// W2T[k*64+c] = pa_w2[c][k]                     (16384)
// WLAT[(ci*64+co)*9+kk] = la_w[co][ci][kk]*g[co]*BNS  (36864)
// F1T[j*64+c] = fuse1_w[c][j]                   (8192)
__global__ __launch_bounds__(256) void k_wprep(const float* __restrict__ pa_w1,
    const float* __restrict__ pa_g, const float* __restrict__ pa_w2,
    const float* __restrict__ la_w, const float* __restrict__ la_g,
    const float* __restrict__ f1w,
    float* __restrict__ W1F, float* __restrict__ W2T, float* __restrict__ WLAT,
    float* __restrict__ F1T) {
  int i = blockIdx.x * 256 + threadIdx.x;
  if (i < 16384) {
    W1F[i] = pa_w1[i] * (pa_g[i >> 6] * BNS);
  } else if (i < 32768) {
    int j = i - 16384; int k = j >> 6, c = j & 63;
    W2T[j] = pa_w2[c * 256 + k];
  } else if (i < 69632) {
    int j = i - 32768; int ci = j / 576, r = j % 576, co = r / 9, kk = r % 9;
    WLAT[j] = la_w[(co * 64 + ci) * 9 + kk] * (la_g[co] * BNS);
  } else if (i < 77824) {
    int j = i - 69632; int jj = j >> 6, c = j & 63;
    F1T[j] = f1w[c * 128 + jj];
  }
}

// ---------------- weight prep #2 (GA-phase weights, written after MRA frees R-tail) ---------
__global__ __launch_bounds__(256) void k_wprep2(const float* __restrict__ f2w,
    const float* __restrict__ p1w, const float* __restrict__ c1w,
    const float* __restrict__ c2w, const float* __restrict__ cvw,
    const float* __restrict__ p2w,
    float* __restrict__ F2T, float* __restrict__ P1T, float* __restrict__ C1T,
    float* __restrict__ C2T, float* __restrict__ CVT, float* __restrict__ P2T) {
  int i = blockIdx.x * 256 + threadIdx.x;
  if (i < 8192) { int jj = i >> 6, c = i & 63; F2T[i] = f2w[c * 128 + jj]; }
  else if (i < 12288) { int j = i - 8192;  int jj = j >> 6, c = j & 63; P1T[j] = p1w[c * 64 + jj]; }
  else if (i < 14336) { int j = i - 12288; int jj = j >> 5, c = j & 31; C1T[j] = c1w[c * 64 + jj]; }
  else if (i < 16384) { int j = i - 14336; int jj = j >> 5, c = j & 31; C2T[j] = c2w[c * 64 + jj]; }
  else if (i < 18432) { int j = i - 16384; int jj = j >> 6, c = j & 63; CVT[j] = cvw[c * 32 + jj]; }
  else if (i < 22528) { int j = i - 18432; int jj = j >> 6, c = j & 63; P2T[j] = p2w[c * 64 + jj]; }
}

// ---------------- PA branch v2: pixel-per-thread, scalar weights, all-register --------------
// 576 blocks x 256 thr = 147456 threads = one per pixel.
__global__ __launch_bounds__(256, 1) void k_pa(const float* __restrict__ x,
    const float* __restrict__ w1f, const float* __restrict__ b1,
    const float* __restrict__ w2t, float* __restrict__ x1pa, bf16* __restrict__ xa) {
  int idx = blockIdx.x * 256 + threadIdx.x;
  int b = idx / 9216, hw = idx % 9216;
  const float* px = x + (size_t)b * 256 * 9216 + hw;
  float xr[64];
#pragma unroll
  for (int j = 0; j < 64; ++j) xr[j] = px[j * 9216];
  float acc[64];
#pragma unroll
  for (int c = 0; c < 64; ++c) acc[c] = 0.f;
  for (int k = 0; k < 256; ++k) {
    const float* wr = w1f + k * 64;
    float h0 = 0.f, h1 = 0.f, h2 = 0.f, h3 = 0.f;
#pragma unroll
    for (int j = 0; j < 64; j += 4) {
      h0 += wr[j] * xr[j];
      h1 += wr[j + 1] * xr[j + 1];
      h2 += wr[j + 2] * xr[j + 2];
      h3 += wr[j + 3] * xr[j + 3];
    }
    float h = geluf((h0 + h1) + (h2 + h3) + b1[k]);
    const float* w2r = w2t + k * 64;
#pragma unroll
    for (int c = 0; c < 64; ++c) acc[c] += w2r[c] * h;
  }
#pragma unroll
  for (int c = 0; c < 64; ++c) {
    float x1v = xr[c];
    float pa = x1v * sigmf(acc[c]);
    x1pa[((size_t)b * 64 + c) * 9216 + hw] = pa;
    xa[((size_t)b * 256 + c) * 9216 + hw] = __float2bfloat16(x1v + pa);
  }
}

// ---------------- generic 1x1 conv v2: pixel-per-thread, transposed scalar weights ----------
template<int COUT>
__global__ __launch_bounds__(256, 1) void k_c1(const float* __restrict__ inA, int CinA,
    const float* __restrict__ xsrc, int xoff, int CinB,
    const float* __restrict__ wt, const float* __restrict__ bias, int act,
    float* __restrict__ out, int npix) {
  int idx = blockIdx.x * 256 + threadIdx.x;
  int b = idx / npix, hw = idx % npix;
  float acc[COUT];
#pragma unroll
  for (int c = 0; c < COUT; ++c) acc[c] = 0.f;
  const float* pA = inA + (size_t)b * CinA * npix + hw;
#pragma unroll 4
  for (int j = 0; j < CinA; ++j) {
    float v = pA[(size_t)j * npix];
    const float* wr = wt + j * COUT;
#pragma unroll
    for (int c = 0; c < COUT; ++c) acc[c] += wr[c] * v;
  }
  if (CinB) {
    const float* pB = xsrc + ((size_t)b * 256 + xoff) * 9216 + hw;
#pragma unroll 4
    for (int j = 0; j < CinB; ++j) {
      float v = pB[(size_t)j * 9216];
      const float* wr = wt + (CinA + j) * COUT;
#pragma unroll
      for (int c = 0; c < COUT; ++c) acc[c] += wr[c] * v;
    }
  }
#pragma unroll
  for (int c = 0; c < COUT; ++c) {
    float r = acc[c] + (bias ? bias[c] : 0.f);
    if (act) r = geluf(r);
    out[((size_t)b * COUT + c) * npix + hw] = r;
  }
}

// ---------------- la v2: 3x3 conv 64->64, all 64 outputs per block, scalar weights ----------
// 576 blocks (b*36+tile), 256 thr = one 16x16 pixel tile. WLAT has BN-g folded.
__global__ __launch_bounds__(256, 1) void k_la(const float* __restrict__ in,
    const float* __restrict__ wlat, const float* __restrict__ bb, bf16* __restrict__ xa) {
  int bid = blockIdx.x;
  int tile = bid % 36, b = bid / 36;
  int th0 = (tile / 6) * 16, tw0 = (tile % 6) * 16;
  int t = threadIdx.x, ty = t >> 4, tx = t & 15;
  __shared__ float s[16][18][18];
  float acc[64];
#pragma unroll
  for (int c = 0; c < 64; ++c) acc[c] = 0.f;
  for (int cc = 0; cc < 4; ++cc) {
    __syncthreads();
    for (int i = t; i < 16 * 324; i += 256) {
      int ci = i / 324, r = i % 324, iy = r / 18, ix = r % 18;
      int y = th0 - 1 + iy, xx = tw0 - 1 + ix;
      float v = 0.f;
      if ((unsigned)y < 96u && (unsigned)xx < 96u)
        v = in[((size_t)(b * 64 + cc * 16 + ci)) * 9216 + y * 96 + xx];
      s[ci][iy][ix] = v;
    }
    __syncthreads();
    for (int ci = 0; ci < 16; ++ci) {
      float v00 = s[ci][ty][tx],     v01 = s[ci][ty][tx + 1],     v02 = s[ci][ty][tx + 2];
      float v10 = s[ci][ty + 1][tx], v11 = s[ci][ty + 1][tx + 1], v12 = s[ci][ty + 1][tx + 2];
      float v20 = s[ci][ty + 2][tx], v21 = s[ci][ty + 2][tx + 1], v22 = s[ci][ty + 2][tx + 2];
      const float* wr = wlat + (cc * 16 + ci) * 576;
#pragma unroll
      for (int co = 0; co < 64; ++co) {
        const float* w9 = wr + co * 9;
        acc[co] += w9[0] * v00 + w9[1] * v01 + w9[2] * v02
                 + w9[3] * v10 + w9[4] * v11 + w9[5] * v12
                 + w9[6] * v20 + w9[7] * v21 + w9[8] * v22;
      }
    }
  }
  size_t base = ((size_t)b * 256 + 64) * 9216 + (th0 + ty) * 96 + (tw0 + tx);
#pragma unroll
  for (int co = 0; co < 64; ++co)
    xa[base + (size_t)co * 9216] = __float2bfloat16(geluf(acc[co] + bb[co]));
}

// ---------------- maxpool3 -------------------------------------------------------------------
__global__ __launch_bounds__(256) void k_maxpool3(const float* __restrict__ x, float* __restrict__ out) {
  int idx = blockIdx.x * 256 + threadIdx.x;
  if (idx >= 16 * 64 * 9216) return;
  int wpx = idx % 96; int tmp = idx / 96; int h = tmp % 96; tmp /= 96; int c = tmp % 64; int b = tmp / 64;
  const float* src = x + (b * 256 + 128 + c) * 9216;
  float m = -3.4e38f;
  for (int dy = -1; dy <= 1; ++dy) {
    int y = h + dy; if ((unsigned)y >= 96u) continue;
    for (int dx = -1; dx <= 1; ++dx) {
      int xx = wpx + dx; if ((unsigned)xx >= 96u) continue;
      m = fmaxf(m, src[y * 96 + xx]);
    }
  }
  out[idx] = m;
}

// ---------------- blurpool -------------------------------------------------------------------
__global__ __launch_bounds__(256) void k_blur(const float* __restrict__ in, float* __restrict__ out) {
  int idx = blockIdx.x * 256 + threadIdx.x;
  if (idx >= 16 * 64 * 1024) return;
  int ow = idx % 32; int tmp = idx / 32; int oh = tmp % 32; int bc = tmp / 32;
  const float* src = in + bc * 9216;
  const float a4[4] = {1.f, 3.f, 3.f, 1.f};
  float s = 0.f;
  for (int ky = 0; ky < 4; ++ky) {
    int sy = 3 * oh + ky - 1; if (sy < 0) sy = -sy; if (sy > 95) sy = 190 - sy;
    for (int kx = 0; kx < 4; ++kx) {
      int sx = 3 * ow + kx - 1; if (sx < 0) sx = -sx; if (sx > 95) sx = 190 - sx;
      s += a4[ky] * a4[kx] * src[sy * 96 + sx];
    }
  }
  out[idx] = s * (1.0f / 64.0f);
}

// ---------------- generic depthwise conv ----------------------------------------------------
__global__ __launch_bounds__(256) void k_dw(const float* __restrict__ in, const float* __restrict__ w,
    const float* __restrict__ bias, float* __restrict__ out,
    int H, int W, int KH, int KW, int pH, int pW, int dil, int accf) {
  int idx = blockIdx.x * 256 + threadIdx.x;
  int total = 16 * 64 * H * W; if (idx >= total) return;
  int wpx = idx % W; int tmp = idx / W; int h = tmp % H; tmp /= H; int c = tmp % 64;
  const float* src = in + tmp * H * W;
  const float* wr = w + c * KH * KW;
  float a = bias ? bias[c] : 0.f;
  for (int ky = 0; ky < KH; ++ky) {
    int y = h - pH + ky * dil; if ((unsigned)y >= (unsigned)H) continue;
    for (int kx = 0; kx < KW; ++kx) {
      int xx = wpx - pW + kx * dil; if ((unsigned)xx >= (unsigned)W) continue;
      a += wr[ky * KW + kx] * src[y * W + xx];
    }
  }
  if (accf) out[idx] += a; else out[idx] = a;
}

// ---------------- shear transforms ----------------------------------------------------------
__global__ __launch_bounds__(256) void k_htrans(const float* __restrict__ in, float* __restrict__ out) {
  int idx = blockIdx.x * 256 + threadIdx.x;
  if (idx >= 16 * 64 * 32 * 63) return;
  int j = idx % 63; int tmp = idx / 63; int i = tmp % 32; int bc = tmp / 32;
  int k = j - i;
  out[idx] = (k >= 0 && k < 32) ? in[(bc * 32 + i) * 32 + k] : 0.f;
}
__global__ __launch_bounds__(256) void k_invh_add(const float* __restrict__ F, float* __restrict__ D) {
  int idx = blockIdx.x * 256 + threadIdx.x;
  if (idx >= 16 * 64 * 1024) return;
  int j = idx % 32; int tmp = idx / 32; int i = tmp % 32; int bc = tmp / 32;
  D[idx] += F[(bc * 32 + i) * 63 + i + j];
}
__global__ __launch_bounds__(256) void k_vtrans(const float* __restrict__ in, float* __restrict__ out) {
  int idx = blockIdx.x * 256 + threadIdx.x;
  if (idx >= 16 * 64 * 63 * 32) return;
  int c = idx % 32; int tmp = idx / 32; int r = tmp % 63; int bc = tmp / 63;
  int k = r - c;
  out[idx] = (k >= 0 && k < 32) ? in[(bc * 32 + k) * 32 + c] : 0.f;
}
__global__ __launch_bounds__(256) void k_invv_add(const float* __restrict__ F, float* __restrict__ D) {
  int idx = blockIdx.x * 256 + threadIdx.x;
  if (idx >= 16 * 64 * 1024) return;
  int j = idx % 32; int tmp = idx / 32; int i = tmp % 32; int bc = tmp / 32;
  D[idx] += F[(bc * 63 + (i + j)) * 32 + j];
}

// ---------------- gate ----------------------------------------------------------------------
__global__ __launch_bounds__(256) void k_gate(const float* __restrict__ D, const float* __restrict__ x,
    const float* __restrict__ g, const float* __restrict__ bb,
    float* __restrict__ mra_out, bf16* __restrict__ xa) {
  int idx = blockIdx.x * 256 + threadIdx.x;
  if (idx >= 16 * 64 * 9216) return;
  int wv = idx % 96; int tmp = idx / 96; int h = tmp % 96; tmp /= 96; int c = tmp % 64; int b = tmp / 64;
  float d = D[((b * 64 + c) * 32 + h / 3) * 32 + (wv / 3)];
  float gt = sigmf(d * g[c] * BNS + bb[c]);
  float x3v = x[(b * 256 + 128 + c) * 9216 + h * 96 + wv];
  float mra = x3v * gt;
  mra_out[idx] = mra;
  xa[(b * 256 + 128 + c) * 9216 + h * 96 + wv] = __float2bfloat16(x3v + mra);
}

// ---------------- maxpool2 with argmax ------------------------------------------------------
__global__ __launch_bounds__(256) void k_pool2(const float* __restrict__ in, float* __restrict__ out,
                                               int* __restrict__ idxo) {
  int idx = blockIdx.x * 256 + threadIdx.x;
  if (idx >= 16 * 64 * 2304) return;
  int ow = idx % 48; int tmp = idx / 48; int oh = tmp % 48; int bc = tmp / 48;
  const float* src = in + bc * 9216;
  int y = 2 * oh, xx = 2 * ow;
  float v0 = src[y * 96 + xx], v1 = src[y * 96 + xx + 1];
  float v2 = src[(y + 1) * 96 + xx], v3 = src[(y + 1) * 96 + xx + 1];
  float best = v0; int bi = 0;
  if (v1 > best) { best = v1; bi = 1; }
  if (v2 > best) { best = v2; bi = 2; }
  if (v3 > best) { best = v3; bi = 3; }
  out[idx] = best; idxo[idx] = bi;
}

// ---------------- channel mean/max ----------------------------------------------------------
__global__ __launch_bounds__(256) void k_agg(const float* __restrict__ J, const float* __restrict__ K,
                                             float* __restrict__ AGG) {
  int idx = blockIdx.x * 256 + threadIdx.x;
  if (idx >= 16 * 2304) return;
  int hw = idx % 2304; int b = idx / 2304;
  float sum = 0.f, mx = -3.4e38f;
  for (int j = 0; j < 32; ++j) { float v = J[(b * 32 + j) * 2304 + hw]; sum += v; mx = fmaxf(mx, v); }
  for (int j = 0; j < 32; ++j) { float v = K[(b * 32 + j) * 2304 + hw]; sum += v; mx = fmaxf(mx, v); }
  AGG[(b * 2 + 0) * 2304 + hw] = sum * (1.0f / 64.0f);
  AGG[(b * 2 + 1) * 2304 + hw] = mx;
}

// ---------------- squeeze conv 2->2 7x7 pad3 + sigmoid --------------------------------------
__global__ __launch_bounds__(256) void k_sq(const float* __restrict__ AGG, const float* __restrict__ w,
                                            const float* __restrict__ bias, float* __restrict__ SG) {
  int idx = blockIdx.x * 256 + threadIdx.x;
  if (idx >= 16 * 2 * 2304) return;
  int hw = idx % 2304; int tmp = idx / 2304; int co = tmp % 2; int b = tmp / 2;
  int h = hw / 48, wv = hw % 48;
  float acc = bias[co];
  for (int ci = 0; ci < 2; ++ci) {
    const float* src = AGG + (b * 2 + ci) * 2304;
    for (int ky = 0; ky < 7; ++ky) {
      int y = h - 3 + ky; if ((unsigned)y >= 48u) continue;
      for (int kx = 0; kx < 7; ++kx) {
        int xx = wv - 3 + kx; if ((unsigned)xx >= 48u) continue;
        acc += w[((co * 2 + ci) * 7 + ky) * 7 + kx] * src[y * 48 + xx];
      }
    }
  }
  SG[idx] = sigmf(acc);
}

__global__ __launch_bounds__(256) void k_mix(const float* __restrict__ J, const float* __restrict__ K,
                                             const float* __restrict__ SG, float* __restrict__ L) {
  int idx = blockIdx.x * 256 + threadIdx.x;
  if (idx >= 16 * 32 * 2304) return;
  int hw = idx % 2304; int tmp = idx / 2304; int b = tmp / 32;
  L[idx] = J[idx] * SG[(b * 2) * 2304 + hw] + K[idx] * SG[(b * 2 + 1) * 2304 + hw];
}

__global__ __launch_bounds__(256) void k_mul(const float* __restrict__ A, const float* __restrict__ B,
                                             float* __restrict__ O) {
  int idx = blockIdx.x * 256 + threadIdx.x;
  if (idx >= 16 * 64 * 2304) return;
  O[idx] = A[idx] * B[idx];
}

// ---------------- unpool + bn(n4), xa ch192..255 --------------------------------------------
__global__ __launch_bounds__(256) void k_unpool(const float* __restrict__ N2, const int* __restrict__ IDX,
    const float* __restrict__ x, const float* __restrict__ g, const float* __restrict__ bb,
    bf16* __restrict__ xa) {
  int idx = blockIdx.x * 256 + threadIdx.x;
  if (idx >= 16 * 64 * 9216) return;
  int wv = idx % 96; int tmp = idx / 96; int h = tmp % 96; tmp /= 96; int c = tmp % 64; int b = tmp / 64;
  int oh = h >> 1, ow = wv >> 1;
  int pos = (b * 64 + c) * 2304 + oh * 48 + ow;
  int kk = (h & 1) * 2 + (wv & 1);
  float v = (IDX[pos] == kk) ? N2[pos] : 0.f;
  float x4v = x[(b * 256 + 192 + c) * 9216 + h * 96 + wv];
  xa[(b * 256 + 192 + c) * 9216 + h * 96 + wv] =
      __float2bfloat16((x4v + v) * g[c] * BNS + bb[c]);
}

// ---------------- transpose XA (ch-major bf16) -> XAT (pixel-major bf16) --------------------
__global__ __launch_bounds__(256) void k_tr(const unsigned short* __restrict__ XA,
                                            unsigned short* __restrict__ XAT) {
  __shared__ unsigned s[64][65];
  int t = threadIdx.x;
  int bid = blockIdx.x;
  int ct = bid & 3;
  int pt = (bid >> 2) % 144;
  int b = (bid >> 2) / 144;
  int c0 = ct * 64, p0 = pt * 64;
  for (int i = t; i < 4096; i += 256) {
    int cl = i >> 6, pl = i & 63;
    s[cl][pl] = XA[(size_t)(b * 256 + c0 + cl) * 9216 + p0 + pl];
  }
  __syncthreads();
  for (int i = t; i < 4096; i += 256) {
    int pl = i >> 6, cl = i & 63;
    XAT[((size_t)(b * 9216 + p0 + pl) << 8) + c0 + cl] = (unsigned short)s[cl][pl];
  }
}

// ---------------- prep: pack weights frag-linear, bf16, BN scales folded --------------------
__global__ __launch_bounds__(256) void k_prep(const float* __restrict__ w1, const float* __restrict__ g1,
    const float* __restrict__ w2, const float* __restrict__ ng,
    unsigned short* __restrict__ w1p, unsigned short* __restrict__ w2p) {
  int i = blockIdx.x * 256 + threadIdx.x;
  if (i >= 262144) return;
  {
    int j = i & 7, lane = (i >> 3) & 63, ks = (i >> 9) & 7, mb = i >> 12;
    int h = mb * 16 + (lane & 15);
    int k = ks * 32 + (lane >> 4) * 8 + j;
    w1p[i] = f2b(w1[h * 256 + k] * (g1[h] * BNS));
  }
  {
    int j = i & 7, lane = (i >> 3) & 63, mb = (i >> 9) & 15, c = i >> 13;
    int m = mb * 16 + (lane & 15);
    int k = c * 32 + (lane >> 4) * 8 + j;
    w2p[i] = f2b(w2[m * 1024 + k] * (ng[m] * BNS));
  }
}

// ---------------- fused MFMA MLP v2: blocked GEMM, B-in-registers, W staged in LDS ----------
__global__ __launch_bounds__(256, 2) void k_mlp_mfma(
    const unsigned short* __restrict__ XAT,
    const unsigned short* __restrict__ W1P, const float* __restrict__ b1,
    const unsigned short* __restrict__ W2P, const float* __restrict__ nbv,
    const float* __restrict__ xin, float* __restrict__ out) {
  __shared__ uint4 w1c4[1024];
  __shared__ uint4 w2c4[1024];
  __shared__ unsigned short hs[128][56];
  __shared__ float b1s[1024];
  __shared__ float nbs[256];
  unsigned short* w1c = (unsigned short*)w1c4;
  unsigned short* w2c = (unsigned short*)w2c4;
  int t = threadIdx.x;
  int b = blockIdx.x / 72;
  int hw0 = (blockIdx.x % 72) * 128;
  for (int i = t; i < 1024; i += 256) b1s[i] = b1[i];
  nbs[t] = nbv[t];
  int lane = t & 63, wave = t >> 6;
  int lm = lane & 15, lk = lane >> 4;
  bf16x8 Bf[2][8];
  {
    const unsigned short* base = XAT + ((size_t)(b * 9216 + hw0 + wave * 32 + lm) << 8) + lk * 8;
#pragma unroll
    for (int nt2 = 0; nt2 < 2; ++nt2)
#pragma unroll
      for (int ks = 0; ks < 8; ++ks)
        Bf[nt2][ks] = *(const bf16x8*)(base + nt2 * 16 * 256 + ks * 32);
  }
  f32x4 Y[16][2];
#pragma unroll
  for (int i = 0; i < 16; ++i) { Y[i][0] = (f32x4){0,0,0,0}; Y[i][1] = (f32x4){0,0,0,0}; }

  const uint4* g1p = (const uint4*)W1P;
  const uint4* g2p = (const uint4*)W2P;
  for (int c = 0; c < 32; ++c) {
    __syncthreads();
#pragma unroll
    for (int i = 0; i < 4; ++i) {
      int o = i * 256 + t;
      w1c4[o] = g1p[c * 1024 + o];
      w2c4[o] = g2p[c * 1024 + o];
    }
    __syncthreads();
    f32x4 Hc[2][2];
#pragma unroll
    for (int i = 0; i < 2; ++i) { Hc[i][0] = (f32x4){0,0,0,0}; Hc[i][1] = (f32x4){0,0,0,0}; }
#pragma unroll
    for (int ks = 0; ks < 8; ++ks) {
      bf16x8 a0 = *(const bf16x8*)&w1c[(ks * 64 + lane) * 8];
      bf16x8 a1 = *(const bf16x8*)&w1c[((8 + ks) * 64 + lane) * 8];
      Hc[0][0] = __builtin_amdgcn_mfma_f32_16x16x32_bf16(a0, Bf[0][ks], Hc[0][0], 0, 0, 0);
      Hc[0][1] = __builtin_amdgcn_mfma_f32_16x16x32_bf16(a0, Bf[1][ks], Hc[0][1], 0, 0, 0);
      Hc[1][0] = __builtin_amdgcn_mfma_f32_16x16x32_bf16(a1, Bf[0][ks], Hc[1][0], 0, 0, 0);
      Hc[1][1] = __builtin_amdgcn_mfma_f32_16x16x32_bf16(a1, Bf[1][ks], Hc[1][1], 0, 0, 0);
    }
#pragma unroll
    for (int mbl = 0; mbl < 2; ++mbl)
#pragma unroll
      for (int nt2 = 0; nt2 < 2; ++nt2)
#pragma unroll
        for (int r = 0; r < 4; r += 2) {
          int h = c * 32 + mbl * 16 + lk * 4 + r;
          float v0 = geluf(Hc[mbl][nt2][r]     + b1s[h]);
          float v1 = geluf(Hc[mbl][nt2][r + 1] + b1s[h + 1]);
          unsigned u = (unsigned)f2b(v0) | ((unsigned)f2b(v1) << 16);
          *(unsigned*)&hs[wave * 32 + nt2 * 16 + lm][mbl * 16 + lk * 4 + r] = u;
        }
    bf16x8 h0 = *(const bf16x8*)&hs[wave * 32 + lm][lk * 8];
    bf16x8 h1 = *(const bf16x8*)&hs[wave * 32 + 16 + lm][lk * 8];
#pragma unroll
    for (int mb = 0; mb < 16; ++mb) {
      bf16x8 a = *(const bf16x8*)&w2c[(mb * 64 + lane) * 8];
      Y[mb][0] = __builtin_amdgcn_mfma_f32_16x16x32_bf16(a, h0, Y[mb][0], 0, 0, 0);
      Y[mb][1] = __builtin_amdgcn_mfma_f32_16x16x32_bf16(a, h1, Y[mb][1], 0, 0, 0);
    }
  }
#pragma unroll
  for (int mb = 0; mb < 16; ++mb)
#pragma unroll
    for (int nt2 = 0; nt2 < 2; ++nt2)
#pragma unroll
      for (int r = 0; r < 4; ++r) {
        int m = mb * 16 + lk * 4 + r;
        size_t o = (size_t)(b * 256 + m) * 9216 + hw0 + wave * 32 + nt2 * 16 + lm;
        out[o] = Y[mb][nt2][r] + nbs[m] + xin[o];
      }
}

extern "C" void kernel_launch(void* const* d_in, const int* in_sizes, int n_in,
                              void* d_out, int out_size, void* d_ws, size_t ws_size,
                              hipStream_t stream) {
  const float* x        = (const float*)d_in[0];
  const float* pa_w1    = (const float*)d_in[1];
  const float* pa_bn_g  = (const float*)d_in[2];
  const float* pa_bn_b  = (const float*)d_in[3];
  const float* pa_w2    = (const float*)d_in[4];
  const float* fuse1_w  = (const float*)d_in[5];
  const float* la_w     = (const float*)d_in[6];
  const float* la_bn_g  = (const float*)d_in[7];
  const float* la_bn_b  = (const float*)d_in[8];
  const float* h1_w     = (const float*)d_in[9];
  const float* v1_w     = (const float*)d_in[10];
  const float* h2_w     = (const float*)d_in[11];
  const float* v2_w     = (const float*)d_in[12];
  const float* mra_bn_g = (const float*)d_in[13];
  const float* mra_bn_b = (const float*)d_in[14];
  const float* fuse2_w  = (const float*)d_in[15];
  const float* g_p1_w   = (const float*)d_in[16];
  const float* g_p1_b   = (const float*)d_in[17];
  const float* g_c0_w   = (const float*)d_in[18];
  const float* g_c0_b   = (const float*)d_in[19];
  const float* g_cs_w   = (const float*)d_in[20];
  const float* g_cs_b   = (const float*)d_in[21];
  const float* g_c1_w   = (const float*)d_in[22];
  const float* g_c1_b   = (const float*)d_in[23];
  const float* g_c2_w   = (const float*)d_in[24];
  const float* g_c2_b   = (const float*)d_in[25];
  const float* g_sq_w   = (const float*)d_in[26];
  const float* g_sq_b   = (const float*)d_in[27];
  const float* g_cv_w   = (const float*)d_in[28];
  const float* g_cv_b   = (const float*)d_in[29];
  const float* g_p2_w   = (const float*)d_in[30];
  const float* g_p2_b   = (const float*)d_in[31];
  const float* n4_g     = (const float*)d_in[32];
  const float* n4_b     = (const float*)d_in[33];
  const float* mlp_w1   = (const float*)d_in[34];
  const float* mlp_bn_g = (const float*)d_in[35];
  const float* mlp_bn_b = (const float*)d_in[36];
  const float* mlp_w2   = (const float*)d_in[37];
  const float* n1_g     = (const float*)d_in[38];
  const float* n1_b     = (const float*)d_in[39];

  // ---- aliased workspace: 44,236,800 floats = 176.9 MB ----
  float* ws = (float*)d_ws;
  bf16*  XA = (bf16*)ws;                    // (16,256,96,96) bf16 = 18,874,368 f-slots
  float* P  = ws + 18874368;                // 9,437,184 f
  float* Q  = ws + 28311552;                // 9,437,184 f
  float* R  = ws + 37748736;                // 6,225,920 f
  float* T  = R;
  float* D  = R + 1048576;
  float* E  = R + 2097152;
  float* F  = R + 4161536;
  float* C48 = P;
  int*   IDX = (int*)(P + 2359296);
  float* G   = P + 4718592;
  float* H2  = P + 7077888;
  float* I2  = Q;
  float* M   = Q + 2359296;
  float* XM  = Q + 4718592;
  float* N2  = Q + 7077888;
  float* J   = R;
  float* K2  = R + 1179648;
  float* L   = R + 2359296;
  float* AGG = R + 3538944;
  float* SG  = R + 3612672;
  unsigned short* XAT = (unsigned short*)P;
  unsigned short* W1P = (unsigned short*)(ws + 43974656);
  unsigned short* W2P = (unsigned short*)(ws + 43974656 + 131072);

  // Early transposed/folded weights: live in R head (T slot), dead before k_blur writes T.
  float* W1F  = R;            // 16384
  float* W2T  = R + 16384;    // 16384
  float* WLAT = R + 32768;    // 36864
  float* F1T  = R + 69632;    // 8192 (ends R+77824 < 1048576)
  // GA-phase transposed weights: R tail (after SG end 3686400), written post-MRA.
  float* GW  = R + 3686400;
  float* F2T = GW;            // 8192
  float* P1T = GW + 8192;     // 4096
  float* C1T = GW + 12288;    // 2048
  float* C2T = GW + 14336;    // 2048
  float* CVT = GW + 16384;    // 2048
  float* P2T = GW + 18432;    // 4096 (ends GW+22528 < 2539520)

  // Prep
  k_prep<<<1024, 256, 0, stream>>>(mlp_w1, mlp_bn_g, mlp_w2, n1_g, W1P, W2P);
  k_wprep<<<304, 256, 0, stream>>>(pa_w1, pa_bn_g, pa_w2, la_w, la_bn_g, fuse1_w,
                                   W1F, W2T, WLAT, F1T);
  // Branch 1 (PA)
  k_pa<<<576, 256, 0, stream>>>(x, W1F, pa_bn_b, W2T, P, XA);
  // Branch 2: fuse1 -> Q; la -> xa ch 64..127
  k_c1<64><<<576, 256, 0, stream>>>(P, 64, x, 64, 64, F1T, (const float*)nullptr, 0, Q, 9216);
  k_la<<<576, 256, 0, stream>>>(Q, WLAT, la_bn_b, XA);
  // Branch 3 (MRA)
  k_maxpool3<<<36864, 256, 0, stream>>>(x, P);
  k_blur<<<4096, 256, 0, stream>>>(P, T);
  k_dw<<<4096, 256, 0, stream>>>(T, h1_w, (const float*)nullptr, D, 32, 32, 7, 3, 3, 1, 1, 0);
  k_dw<<<4096, 256, 0, stream>>>(T, v1_w, (const float*)nullptr, D, 32, 32, 3, 7, 1, 3, 1, 1);
  k_htrans<<<8064, 256, 0, stream>>>(T, E);
  k_dw<<<8064, 256, 0, stream>>>(E, h2_w, (const float*)nullptr, F, 32, 63, 7, 3, 3, 1, 1, 0);
  k_invh_add<<<4096, 256, 0, stream>>>(F, D);
  k_vtrans<<<8064, 256, 0, stream>>>(T, E);
  k_dw<<<8064, 256, 0, stream>>>(E, v2_w, (const float*)nullptr, F, 63, 32, 3, 7, 1, 3, 1, 0);
  k_invv_add<<<4096, 256, 0, stream>>>(F, D);
  k_gate<<<36864, 256, 0, stream>>>(D, x, mra_bn_g, mra_bn_b, P, XA);
  // Branch 4 (GA)
  k_wprep2<<<88, 256, 0, stream>>>(fuse2_w, g_p1_w, g_c1_w, g_c2_w, g_cv_w, g_p2_w,
                                   F2T, P1T, C1T, C2T, CVT, P2T);
  k_c1<64><<<576, 256, 0, stream>>>(P, 64, x, 192, 64, F2T, (const float*)nullptr, 0, Q, 9216);
  k_pool2<<<9216, 256, 0, stream>>>(Q, C48, IDX);
  k_c1<64><<<144, 256, 0, stream>>>(C48, 64, (const float*)nullptr, 0, 0, P1T, g_p1_b, 1, G, 2304);
  k_dw<<<9216, 256, 0, stream>>>(G, g_c0_w, g_c0_b, H2, 48, 48, 5, 5, 2, 2, 1, 0);
  k_dw<<<9216, 256, 0, stream>>>(H2, g_cs_w, g_cs_b, I2, 48, 48, 7, 7, 9, 9, 3, 0);
  k_c1<32><<<144, 256, 0, stream>>>(H2, 64, (const float*)nullptr, 0, 0, C1T, g_c1_b, 0, J, 2304);
  k_c1<32><<<144, 256, 0, stream>>>(I2, 64, (const float*)nullptr, 0, 0, C2T, g_c2_b, 0, K2, 2304);
  k_agg<<<144, 256, 0, stream>>>(J, K2, AGG);
  k_sq<<<288, 256, 0, stream>>>(AGG, g_sq_w, g_sq_b, SG);
  k_mix<<<4608, 256, 0, stream>>>(J, K2, SG, L);
  k_c1<64><<<144, 256, 0, stream>>>(L, 32, (const float*)nullptr, 0, 0, CVT, g_cv_b, 0, M, 2304);
  k_mul<<<9216, 256, 0, stream>>>(G, M, XM);
  k_c1<64><<<144, 256, 0, stream>>>(XM, 64, (const float*)nullptr, 0, 0, P2T, g_p2_b, 0, N2, 2304);
  k_unpool<<<36864, 256, 0, stream>>>(N2, IDX, x, n4_g, n4_b, XA);
  // Transpose xa -> pixel-major
  k_tr<<<9216, 256, 0, stream>>>((const unsigned short*)XA, XAT);
  // MLP + residual
  k_mlp_mfma<<<1152, 256, 0, stream>>>(XAT, W1P, mlp_bn_b, W2P, n1_b, x, (float*)d_out);
}

// Round 5
// 1282.580 us; speedup vs baseline: 1.7853x; 1.7853x over previous
//
#include <hip/hip_runtime.h>
#include <hip/hip_bf16.h>

typedef __hip_bfloat16 bf16;
typedef short bf16x8 __attribute__((ext_vector_type(8)));
typedef float f32x4 __attribute__((ext_vector_type(4)));

#define BNS 0.9999950000374997f  /* 1/sqrt(1+1e-5) */

__device__ __forceinline__ float geluf(float x) { return 0.5f * x * (1.0f + erff(x * 0.70710678118654752f)); }
__device__ __forceinline__ float sigmf(float x) { return 1.0f / (1.0f + expf(-x)); }
__device__ __forceinline__ unsigned short f2b(float f) { bf16 h = __float2bfloat16(f); return *(unsigned short*)&h; }

// ============ weight prep #1: bf16 frag-linear packs (PA, LA, fuse1) ========================
// Generic frag layout: idx = ((kc*MT + mb)*64 + lane)*8 + j
//   m = mb*16 + (lane&15), k = kc*32 + (lane>>4)*8 + j
// W1PA: M=256 hidden (MT=16), K=64 ch, fold pa_g*BNS          (16384 sh)
// W2PA: M=64 out (MT=4), K=256 hidden                          (16384 sh)
// WLAP: M=64 co (MT=4), K-chunk gk = tap*2+kc2, fold la_g*BNS  (36864 sh)
// F1P : M=64 (MT=4), K=128                                     (8192 sh)
__global__ __launch_bounds__(256) void k_wprep(const float* __restrict__ pa_w1,
    const float* __restrict__ pa_g, const float* __restrict__ pa_w2,
    const float* __restrict__ la_w, const float* __restrict__ la_g,
    const float* __restrict__ f1w,
    unsigned short* __restrict__ W1PA, unsigned short* __restrict__ W2PA,
    unsigned short* __restrict__ WLAP, unsigned short* __restrict__ F1P) {
  int i = blockIdx.x * 256 + threadIdx.x;
  if (i < 16384) {
    int j = i & 7, lane = (i >> 3) & 63, q = i >> 9;
    int mb = q % 16, kc = q / 16;
    int m = mb * 16 + (lane & 15), k = kc * 32 + (lane >> 4) * 8 + j;
    W1PA[i] = f2b(pa_w1[m * 64 + k] * (pa_g[m] * BNS));
  } else if (i < 32768) {
    int ii = i - 16384;
    int j = ii & 7, lane = (ii >> 3) & 63, q = ii >> 9;
    int mb = q % 4, kc = q / 4;
    int m = mb * 16 + (lane & 15), k = kc * 32 + (lane >> 4) * 8 + j;
    W2PA[ii] = f2b(pa_w2[m * 256 + k]);
  } else if (i < 69632) {
    int ii = i - 32768;
    int j = ii & 7, lane = (ii >> 3) & 63, q = ii >> 9;
    int mb = q % 4, gk = q / 4;           // gk = tap*2 + kc2, tap = ky*3+kx
    int tap = gk >> 1, kc2 = gk & 1;
    int co = mb * 16 + (lane & 15), ci = kc2 * 32 + (lane >> 4) * 8 + j;
    WLAP[ii] = f2b(la_w[(co * 64 + ci) * 9 + tap] * (la_g[co] * BNS));
  } else if (i < 77824) {
    int ii = i - 69632;
    int j = ii & 7, lane = (ii >> 3) & 63, q = ii >> 9;
    int mb = q % 4, kc = q / 4;
    int m = mb * 16 + (lane & 15), k = kc * 32 + (lane >> 4) * 8 + j;
    F1P[ii] = f2b(f1w[m * 128 + k]);
  }
}

// ============ weight prep #2: GA-phase packs (after MRA frees R-tail) =======================
__global__ __launch_bounds__(256) void k_wprep2(const float* __restrict__ f2w,
    const float* __restrict__ p1w, const float* __restrict__ c1w,
    const float* __restrict__ c2w, const float* __restrict__ cvw,
    const float* __restrict__ p2w,
    unsigned short* __restrict__ F2P, unsigned short* __restrict__ P1P,
    unsigned short* __restrict__ C1P, unsigned short* __restrict__ C2P,
    unsigned short* __restrict__ CVP, unsigned short* __restrict__ P2P) {
  int i = blockIdx.x * 256 + threadIdx.x;
  if (i < 8192) {               // fuse2: MT=4, K=128
    int j = i & 7, lane = (i >> 3) & 63, q = i >> 9;
    int mb = q % 4, kc = q / 4;
    int m = mb * 16 + (lane & 15), k = kc * 32 + (lane >> 4) * 8 + j;
    F2P[i] = f2b(f2w[m * 128 + k]);
  } else if (i < 12288) {       // p1: MT=4, K=64
    int ii = i - 8192;
    int j = ii & 7, lane = (ii >> 3) & 63, q = ii >> 9;
    int mb = q % 4, kc = q / 4;
    int m = mb * 16 + (lane & 15), k = kc * 32 + (lane >> 4) * 8 + j;
    P1P[ii] = f2b(p1w[m * 64 + k]);
  } else if (i < 14336) {       // c1: MT=2, K=64
    int ii = i - 12288;
    int j = ii & 7, lane = (ii >> 3) & 63, q = ii >> 9;
    int mb = q % 2, kc = q / 2;
    int m = mb * 16 + (lane & 15), k = kc * 32 + (lane >> 4) * 8 + j;
    C1P[ii] = f2b(c1w[m * 64 + k]);
  } else if (i < 16384) {       // c2: MT=2, K=64
    int ii = i - 14336;
    int j = ii & 7, lane = (ii >> 3) & 63, q = ii >> 9;
    int mb = q % 2, kc = q / 2;
    int m = mb * 16 + (lane & 15), k = kc * 32 + (lane >> 4) * 8 + j;
    C2P[ii] = f2b(c2w[m * 64 + k]);
  } else if (i < 18432) {       // cv: MT=4, K=32
    int ii = i - 16384;
    int j = ii & 7, lane = (ii >> 3) & 63, q = ii >> 9;
    int mb = q % 4;             // kc = 0
    int m = mb * 16 + (lane & 15), k = (lane >> 4) * 8 + j;
    CVP[ii] = f2b(cvw[m * 32 + k]);
  } else if (i < 22528) {       // p2: MT=4, K=64
    int ii = i - 18432;
    int j = ii & 7, lane = (ii >> 3) & 63, q = ii >> 9;
    int mb = q % 4, kc = q / 4;
    int m = mb * 16 + (lane & 15), k = kc * 32 + (lane >> 4) * 8 + j;
    P2P[ii] = f2b(p2w[m * 64 + k]);
  }
}

// ============ PA branch v3: chained MFMA GEMMs (64 -> 256 gelu -> 64) =======================
// 1152 blocks x 256 thr. Block = 128 px; wave owns 32 px (2 n-tiles).
__global__ __launch_bounds__(256, 2) void k_pa(const float* __restrict__ x,
    const unsigned short* __restrict__ W1PA, const float* __restrict__ b1,
    const unsigned short* __restrict__ W2PA,
    float* __restrict__ x1pa, bf16* __restrict__ xa) {
  __shared__ unsigned short hs[128][40];
  __shared__ float b1s[256];
  int t = threadIdx.x;
  b1s[t] = b1[t];
  __syncthreads();
  int b = blockIdx.x / 72;
  int hw0 = (blockIdx.x % 72) * 128;
  int lane = t & 63, wave = t >> 6, lm = lane & 15, lk = lane >> 4;
  // GEMM1 B-frags: X1[ch=k][px=n], direct global f32 -> bf16
  bf16x8 Bf[2][2];   // [nt][ks]
  {
    const float* xb = x + (size_t)b * 256 * 9216 + hw0 + wave * 32 + lm;
#pragma unroll
    for (int nt = 0; nt < 2; ++nt)
#pragma unroll
      for (int ks = 0; ks < 2; ++ks)
#pragma unroll
        for (int j = 0; j < 8; ++j)
          Bf[nt][ks][j] = (short)f2b(xb[(size_t)(ks * 32 + lk * 8 + j) * 9216 + nt * 16]);
  }
  f32x4 Y[4][2];
#pragma unroll
  for (int i = 0; i < 4; ++i) { Y[i][0] = (f32x4){0,0,0,0}; Y[i][1] = (f32x4){0,0,0,0}; }

  for (int c = 0; c < 8; ++c) {   // hidden chunks of 32
    f32x4 Hc[2][2];
#pragma unroll
    for (int i = 0; i < 2; ++i) { Hc[i][0] = (f32x4){0,0,0,0}; Hc[i][1] = (f32x4){0,0,0,0}; }
#pragma unroll
    for (int ks = 0; ks < 2; ++ks)
#pragma unroll
      for (int mt = 0; mt < 2; ++mt) {
        bf16x8 a = *(const bf16x8*)(W1PA + ((size_t)((ks * 16 + c * 2 + mt) * 64 + lane) * 8));
        Hc[mt][0] = __builtin_amdgcn_mfma_f32_16x16x32_bf16(a, Bf[0][ks], Hc[mt][0], 0, 0, 0);
        Hc[mt][1] = __builtin_amdgcn_mfma_f32_16x16x32_bf16(a, Bf[1][ks], Hc[mt][1], 0, 0, 0);
      }
    // gelu(+bias) -> hs (wave-private rows)
#pragma unroll
    for (int mt = 0; mt < 2; ++mt)
#pragma unroll
      for (int nt = 0; nt < 2; ++nt)
#pragma unroll
        for (int r = 0; r < 4; r += 2) {
          int h = c * 32 + mt * 16 + lk * 4 + r;
          float v0 = geluf(Hc[mt][nt][r]     + b1s[h]);
          float v1 = geluf(Hc[mt][nt][r + 1] + b1s[h + 1]);
          unsigned u = (unsigned)f2b(v0) | ((unsigned)f2b(v1) << 16);
          *(unsigned*)&hs[wave * 32 + nt * 16 + lm][mt * 16 + lk * 4 + r] = u;
        }
    // GEMM2: accumulate Y over this chunk's K=32
    bf16x8 h0 = *(const bf16x8*)&hs[wave * 32 + lm][lk * 8];
    bf16x8 h1 = *(const bf16x8*)&hs[wave * 32 + 16 + lm][lk * 8];
#pragma unroll
    for (int mb = 0; mb < 4; ++mb) {
      bf16x8 a2 = *(const bf16x8*)(W2PA + ((size_t)((c * 4 + mb) * 64 + lane) * 8));
      Y[mb][0] = __builtin_amdgcn_mfma_f32_16x16x32_bf16(a2, h0, Y[mb][0], 0, 0, 0);
      Y[mb][1] = __builtin_amdgcn_mfma_f32_16x16x32_bf16(a2, h1, Y[mb][1], 0, 0, 0);
    }
  }
  // epilogue: sigmoid gate, write x1pa (f32) + xa ch0..63 (bf16)
#pragma unroll
  for (int mb = 0; mb < 4; ++mb)
#pragma unroll
    for (int nt = 0; nt < 2; ++nt)
#pragma unroll
      for (int r = 0; r < 4; ++r) {
        int co = mb * 16 + lk * 4 + r;
        int px = hw0 + wave * 32 + nt * 16 + lm;
        float x1v = x[((size_t)b * 256 + co) * 9216 + px];
        float pa = x1v * sigmf(Y[mb][nt][r]);
        x1pa[((size_t)b * 64 + co) * 9216 + px] = pa;
        xa[((size_t)b * 256 + co) * 9216 + px] = __float2bfloat16(x1v + pa);
      }
}

// ============ generic 1x1 MFMA conv =========================================================
// MT m-tiles (Cout = MT*16); K = (KCA+KCB)*32. Chunks [0,KCA) from inA (ch-major, CinA=KCA*32),
// chunks [KCA,..) from xsrc (256-ch x tensor) at channel xoff. Block = 128 px, 4 waves.
template<int MT, int KCA, int KCB>
__global__ __launch_bounds__(256, 2) void k_cg(const float* __restrict__ inA,
    const float* __restrict__ xsrc, int xoff,
    const unsigned short* __restrict__ wp, const float* __restrict__ bias, int act,
    float* __restrict__ out, int npix) {
  int t = threadIdx.x, lane = t & 63, wave = t >> 6, lm = lane & 15, lk = lane >> 4;
  int p0 = blockIdx.x * 128;
  int b = p0 / npix, hw0 = p0 % npix;
  f32x4 acc[MT][2];
#pragma unroll
  for (int i = 0; i < MT; ++i) { acc[i][0] = (f32x4){0,0,0,0}; acc[i][1] = (f32x4){0,0,0,0}; }
#pragma unroll
  for (int kc = 0; kc < KCA + KCB; ++kc) {
    bf16x8 bf[2];
#pragma unroll
    for (int nt = 0; nt < 2; ++nt) {
      if (kc < KCA) {
        const float* src = inA + ((size_t)b * (KCA * 32) + kc * 32 + lk * 8) * npix
                         + hw0 + wave * 32 + nt * 16 + lm;
#pragma unroll
        for (int j = 0; j < 8; ++j) bf[nt][j] = (short)f2b(src[(size_t)j * npix]);
      } else {
        const float* src = xsrc + ((size_t)b * 256 + xoff + (kc - KCA) * 32 + lk * 8) * 9216
                         + hw0 + wave * 32 + nt * 16 + lm;
#pragma unroll
        for (int j = 0; j < 8; ++j) bf[nt][j] = (short)f2b(src[(size_t)j * 9216]);
      }
    }
#pragma unroll
    for (int mb = 0; mb < MT; ++mb) {
      bf16x8 a = *(const bf16x8*)(wp + ((size_t)((kc * MT + mb) * 64 + lane) * 8));
      acc[mb][0] = __builtin_amdgcn_mfma_f32_16x16x32_bf16(a, bf[0], acc[mb][0], 0, 0, 0);
      acc[mb][1] = __builtin_amdgcn_mfma_f32_16x16x32_bf16(a, bf[1], acc[mb][1], 0, 0, 0);
    }
  }
#pragma unroll
  for (int mb = 0; mb < MT; ++mb)
#pragma unroll
    for (int nt = 0; nt < 2; ++nt)
#pragma unroll
      for (int r = 0; r < 4; ++r) {
        int c = mb * 16 + lk * 4 + r;
        float v = acc[mb][nt][r] + (bias ? bias[c] : 0.f);
        if (act) v = geluf(v);
        out[((size_t)b * (MT * 16) + c) * npix + hw0 + wave * 32 + nt * 16 + lm] = v;
      }
}

// ============ la v3: implicit-GEMM 3x3 conv 64->64 via 9 shifted 1x1s =======================
// 1536 blocks (b*96+py) x 384 thr (6 waves, wave = 16-px n-tile of the row). BN-g in WLAP.
__global__ __launch_bounds__(384, 2) void k_la(const float* __restrict__ Q,
    const unsigned short* __restrict__ WLAP, const float* __restrict__ bb,
    bf16* __restrict__ xa) {
  int py = blockIdx.x % 96, b = blockIdx.x / 96;
  int t = threadIdx.x, lane = t & 63, w = t >> 6, lm = lane & 15, lk = lane >> 4;
  int px = w * 16 + lm;
  f32x4 acc[4];
#pragma unroll
  for (int i = 0; i < 4; ++i) acc[i] = (f32x4){0,0,0,0};
#pragma unroll
  for (int ky = 0; ky < 3; ++ky) {
    int row = py + ky - 1;
    if ((unsigned)row >= 96u) continue;      // uniform: zero-pad row -> skip
#pragma unroll
    for (int kx = 0; kx < 3; ++kx) {
      int pxe = px + kx - 1;
      bool vld = (unsigned)pxe < 96u;        // per-lane horizontal pad
      int pxc = vld ? pxe : 0;
      const float* qb = Q + ((size_t)b * 64 + lk * 8) * 9216 + row * 96 + pxc;
#pragma unroll
      for (int kc = 0; kc < 2; ++kc) {
        bf16x8 bf;
#pragma unroll
        for (int j = 0; j < 8; ++j) {
          float v = vld ? qb[(size_t)(kc * 32 + j) * 9216] : 0.f;
          bf[j] = (short)f2b(v);
        }
        int gk = (ky * 3 + kx) * 2 + kc;
#pragma unroll
        for (int mb = 0; mb < 4; ++mb) {
          bf16x8 a = *(const bf16x8*)(WLAP + ((size_t)((gk * 4 + mb) * 64 + lane) * 8));
          acc[mb] = __builtin_amdgcn_mfma_f32_16x16x32_bf16(a, bf, acc[mb], 0, 0, 0);
        }
      }
    }
  }
#pragma unroll
  for (int mb = 0; mb < 4; ++mb)
#pragma unroll
    for (int r = 0; r < 4; ++r) {
      int co = mb * 16 + lk * 4 + r;
      float v = geluf(acc[mb][r] + bb[co]);
      xa[((size_t)b * 256 + 64 + co) * 9216 + py * 96 + px] = __float2bfloat16(v);
    }
}

// ---------------- maxpool3 -------------------------------------------------------------------
__global__ __launch_bounds__(256) void k_maxpool3(const float* __restrict__ x, float* __restrict__ out) {
  int idx = blockIdx.x * 256 + threadIdx.x;
  if (idx >= 16 * 64 * 9216) return;
  int wpx = idx % 96; int tmp = idx / 96; int h = tmp % 96; tmp /= 96; int c = tmp % 64; int b = tmp / 64;
  const float* src = x + (b * 256 + 128 + c) * 9216;
  float m = -3.4e38f;
  for (int dy = -1; dy <= 1; ++dy) {
    int y = h + dy; if ((unsigned)y >= 96u) continue;
    for (int dx = -1; dx <= 1; ++dx) {
      int xx = wpx + dx; if ((unsigned)xx >= 96u) continue;
      m = fmaxf(m, src[y * 96 + xx]);
    }
  }
  out[idx] = m;
}

// ---------------- blurpool -------------------------------------------------------------------
__global__ __launch_bounds__(256) void k_blur(const float* __restrict__ in, float* __restrict__ out) {
  int idx = blockIdx.x * 256 + threadIdx.x;
  if (idx >= 16 * 64 * 1024) return;
  int ow = idx % 32; int tmp = idx / 32; int oh = tmp % 32; int bc = tmp / 32;
  const float* src = in + bc * 9216;
  const float a4[4] = {1.f, 3.f, 3.f, 1.f};
  float s = 0.f;
  for (int ky = 0; ky < 4; ++ky) {
    int sy = 3 * oh + ky - 1; if (sy < 0) sy = -sy; if (sy > 95) sy = 190 - sy;
    for (int kx = 0; kx < 4; ++kx) {
      int sx = 3 * ow + kx - 1; if (sx < 0) sx = -sx; if (sx > 95) sx = 190 - sx;
      s += a4[ky] * a4[kx] * src[sy * 96 + sx];
    }
  }
  out[idx] = s * (1.0f / 64.0f);
}

// ---------------- generic depthwise conv ----------------------------------------------------
__global__ __launch_bounds__(256) void k_dw(const float* __restrict__ in, const float* __restrict__ w,
    const float* __restrict__ bias, float* __restrict__ out,
    int H, int W, int KH, int KW, int pH, int pW, int dil, int accf) {
  int idx = blockIdx.x * 256 + threadIdx.x;
  int total = 16 * 64 * H * W; if (idx >= total) return;
  int wpx = idx % W; int tmp = idx / W; int h = tmp % H; tmp /= H; int c = tmp % 64;
  const float* src = in + tmp * H * W;
  const float* wr = w + c * KH * KW;
  float a = bias ? bias[c] : 0.f;
  for (int ky = 0; ky < KH; ++ky) {
    int y = h - pH + ky * dil; if ((unsigned)y >= (unsigned)H) continue;
    for (int kx = 0; kx < KW; ++kx) {
      int xx = wpx - pW + kx * dil; if ((unsigned)xx >= (unsigned)W) continue;
      a += wr[ky * KW + kx] * src[y * W + xx];
    }
  }
  if (accf) out[idx] += a; else out[idx] = a;
}

// ---------------- shear transforms ----------------------------------------------------------
__global__ __launch_bounds__(256) void k_htrans(const float* __restrict__ in, float* __restrict__ out) {
  int idx = blockIdx.x * 256 + threadIdx.x;
  if (idx >= 16 * 64 * 32 * 63) return;
  int j = idx % 63; int tmp = idx / 63; int i = tmp % 32; int bc = tmp / 32;
  int k = j - i;
  out[idx] = (k >= 0 && k < 32) ? in[(bc * 32 + i) * 32 + k] : 0.f;
}
__global__ __launch_bounds__(256) void k_invh_add(const float* __restrict__ F, float* __restrict__ D) {
  int idx = blockIdx.x * 256 + threadIdx.x;
  if (idx >= 16 * 64 * 1024) return;
  int j = idx % 32; int tmp = idx / 32; int i = tmp % 32; int bc = tmp / 32;
  D[idx] += F[(bc * 32 + i) * 63 + i + j];
}
__global__ __launch_bounds__(256) void k_vtrans(const float* __restrict__ in, float* __restrict__ out) {
  int idx = blockIdx.x * 256 + threadIdx.x;
  if (idx >= 16 * 64 * 63 * 32) return;
  int c = idx % 32; int tmp = idx / 32; int r = tmp % 63; int bc = tmp / 63;
  int k = r - c;
  out[idx] = (k >= 0 && k < 32) ? in[(bc * 32 + k) * 32 + c] : 0.f;
}
__global__ __launch_bounds__(256) void k_invv_add(const float* __restrict__ F, float* __restrict__ D) {
  int idx = blockIdx.x * 256 + threadIdx.x;
  if (idx >= 16 * 64 * 1024) return;
  int j = idx % 32; int tmp = idx / 32; int i = tmp % 32; int bc = tmp / 32;
  D[idx] += F[(bc * 63 + (i + j)) * 32 + j];
}

// ---------------- gate ----------------------------------------------------------------------
__global__ __launch_bounds__(256) void k_gate(const float* __restrict__ D, const float* __restrict__ x,
    const float* __restrict__ g, const float* __restrict__ bb,
    float* __restrict__ mra_out, bf16* __restrict__ xa) {
  int idx = blockIdx.x * 256 + threadIdx.x;
  if (idx >= 16 * 64 * 9216) return;
  int wv = idx % 96; int tmp = idx / 96; int h = tmp % 96; tmp /= 96; int c = tmp % 64; int b = tmp / 64;
  float d = D[((b * 64 + c) * 32 + h / 3) * 32 + (wv / 3)];
  float gt = sigmf(d * g[c] * BNS + bb[c]);
  float x3v = x[(b * 256 + 128 + c) * 9216 + h * 96 + wv];
  float mra = x3v * gt;
  mra_out[idx] = mra;
  xa[(b * 256 + 128 + c) * 9216 + h * 96 + wv] = __float2bfloat16(x3v + mra);
}

// ---------------- maxpool2 with argmax ------------------------------------------------------
__global__ __launch_bounds__(256) void k_pool2(const float* __restrict__ in, float* __restrict__ out,
                                               int* __restrict__ idxo) {
  int idx = blockIdx.x * 256 + threadIdx.x;
  if (idx >= 16 * 64 * 2304) return;
  int ow = idx % 48; int tmp = idx / 48; int oh = tmp % 48; int bc = tmp / 48;
  const float* src = in + bc * 9216;
  int y = 2 * oh, xx = 2 * ow;
  float v0 = src[y * 96 + xx], v1 = src[y * 96 + xx + 1];
  float v2 = src[(y + 1) * 96 + xx], v3 = src[(y + 1) * 96 + xx + 1];
  float best = v0; int bi = 0;
  if (v1 > best) { best = v1; bi = 1; }
  if (v2 > best) { best = v2; bi = 2; }
  if (v3 > best) { best = v3; bi = 3; }
  out[idx] = best; idxo[idx] = bi;
}

// ---------------- channel mean/max ----------------------------------------------------------
__global__ __launch_bounds__(256) void k_agg(const float* __restrict__ J, const float* __restrict__ K,
                                             float* __restrict__ AGG) {
  int idx = blockIdx.x * 256 + threadIdx.x;
  if (idx >= 16 * 2304) return;
  int hw = idx % 2304; int b = idx / 2304;
  float sum = 0.f, mx = -3.4e38f;
  for (int j = 0; j < 32; ++j) { float v = J[(b * 32 + j) * 2304 + hw]; sum += v; mx = fmaxf(mx, v); }
  for (int j = 0; j < 32; ++j) { float v = K[(b * 32 + j) * 2304 + hw]; sum += v; mx = fmaxf(mx, v); }
  AGG[(b * 2 + 0) * 2304 + hw] = sum * (1.0f / 64.0f);
  AGG[(b * 2 + 1) * 2304 + hw] = mx;
}

// ---------------- squeeze conv 2->2 7x7 pad3 + sigmoid --------------------------------------
__global__ __launch_bounds__(256) void k_sq(const float* __restrict__ AGG, const float* __restrict__ w,
                                            const float* __restrict__ bias, float* __restrict__ SG) {
  int idx = blockIdx.x * 256 + threadIdx.x;
  if (idx >= 16 * 2 * 2304) return;
  int hw = idx % 2304; int tmp = idx / 2304; int co = tmp % 2; int b = tmp / 2;
  int h = hw / 48, wv = hw % 48;
  float acc = bias[co];
  for (int ci = 0; ci < 2; ++ci) {
    const float* src = AGG + (b * 2 + ci) * 2304;
    for (int ky = 0; ky < 7; ++ky) {
      int y = h - 3 + ky; if ((unsigned)y >= 48u) continue;
      for (int kx = 0; kx < 7; ++kx) {
        int xx = wv - 3 + kx; if ((unsigned)xx >= 48u) continue;
        acc += w[((co * 2 + ci) * 7 + ky) * 7 + kx] * src[y * 48 + xx];
      }
    }
  }
  SG[idx] = sigmf(acc);
}

__global__ __launch_bounds__(256) void k_mix(const float* __restrict__ J, const float* __restrict__ K,
                                             const float* __restrict__ SG, float* __restrict__ L) {
  int idx = blockIdx.x * 256 + threadIdx.x;
  if (idx >= 16 * 32 * 2304) return;
  int hw = idx % 2304; int tmp = idx / 2304; int b = tmp / 32;
  L[idx] = J[idx] * SG[(b * 2) * 2304 + hw] + K[idx] * SG[(b * 2 + 1) * 2304 + hw];
}

__global__ __launch_bounds__(256) void k_mul(const float* __restrict__ A, const float* __restrict__ B,
                                             float* __restrict__ O) {
  int idx = blockIdx.x * 256 + threadIdx.x;
  if (idx >= 16 * 64 * 2304) return;
  O[idx] = A[idx] * B[idx];
}

// ---------------- unpool + bn(n4), xa ch192..255 --------------------------------------------
__global__ __launch_bounds__(256) void k_unpool(const float* __restrict__ N2, const int* __restrict__ IDX,
    const float* __restrict__ x, const float* __restrict__ g, const float* __restrict__ bb,
    bf16* __restrict__ xa) {
  int idx = blockIdx.x * 256 + threadIdx.x;
  if (idx >= 16 * 64 * 9216) return;
  int wv = idx % 96; int tmp = idx / 96; int h = tmp % 96; tmp /= 96; int c = tmp % 64; int b = tmp / 64;
  int oh = h >> 1, ow = wv >> 1;
  int pos = (b * 64 + c) * 2304 + oh * 48 + ow;
  int kk = (h & 1) * 2 + (wv & 1);
  float v = (IDX[pos] == kk) ? N2[pos] : 0.f;
  float x4v = x[(b * 256 + 192 + c) * 9216 + h * 96 + wv];
  xa[(b * 256 + 192 + c) * 9216 + h * 96 + wv] =
      __float2bfloat16((x4v + v) * g[c] * BNS + bb[c]);
}

// ---------------- transpose XA (ch-major bf16) -> XAT (pixel-major bf16) --------------------
__global__ __launch_bounds__(256) void k_tr(const unsigned short* __restrict__ XA,
                                            unsigned short* __restrict__ XAT) {
  __shared__ unsigned s[64][65];
  int t = threadIdx.x;
  int bid = blockIdx.x;
  int ct = bid & 3;
  int pt = (bid >> 2) % 144;
  int b = (bid >> 2) / 144;
  int c0 = ct * 64, p0 = pt * 64;
  for (int i = t; i < 4096; i += 256) {
    int cl = i >> 6, pl = i & 63;
    s[cl][pl] = XA[(size_t)(b * 256 + c0 + cl) * 9216 + p0 + pl];
  }
  __syncthreads();
  for (int i = t; i < 4096; i += 256) {
    int pl = i >> 6, cl = i & 63;
    XAT[((size_t)(b * 9216 + p0 + pl) << 8) + c0 + cl] = (unsigned short)s[cl][pl];
  }
}

// ---------------- prep: MLP weights frag-linear, bf16, BN scales folded ---------------------
__global__ __launch_bounds__(256) void k_prep(const float* __restrict__ w1, const float* __restrict__ g1,
    const float* __restrict__ w2, const float* __restrict__ ng,
    unsigned short* __restrict__ w1p, unsigned short* __restrict__ w2p) {
  int i = blockIdx.x * 256 + threadIdx.x;
  if (i >= 262144) return;
  {
    int j = i & 7, lane = (i >> 3) & 63, ks = (i >> 9) & 7, mb = i >> 12;
    int h = mb * 16 + (lane & 15);
    int k = ks * 32 + (lane >> 4) * 8 + j;
    w1p[i] = f2b(w1[h * 256 + k] * (g1[h] * BNS));
  }
  {
    int j = i & 7, lane = (i >> 3) & 63, mb = (i >> 9) & 15, c = i >> 13;
    int m = mb * 16 + (lane & 15);
    int k = c * 32 + (lane >> 4) * 8 + j;
    w2p[i] = f2b(w2[m * 1024 + k] * (ng[m] * BNS));
  }
}

// ---------------- fused MFMA MLP: blocked GEMM, B-in-registers, W staged in LDS -------------
__global__ __launch_bounds__(256, 2) void k_mlp_mfma(
    const unsigned short* __restrict__ XAT,
    const unsigned short* __restrict__ W1P, const float* __restrict__ b1,
    const unsigned short* __restrict__ W2P, const float* __restrict__ nbv,
    const float* __restrict__ xin, float* __restrict__ out) {
  __shared__ uint4 w1c4[1024];
  __shared__ uint4 w2c4[1024];
  __shared__ unsigned short hs[128][56];
  __shared__ float b1s[1024];
  __shared__ float nbs[256];
  unsigned short* w1c = (unsigned short*)w1c4;
  unsigned short* w2c = (unsigned short*)w2c4;
  int t = threadIdx.x;
  int b = blockIdx.x / 72;
  int hw0 = (blockIdx.x % 72) * 128;
  for (int i = t; i < 1024; i += 256) b1s[i] = b1[i];
  nbs[t] = nbv[t];
  int lane = t & 63, wave = t >> 6;
  int lm = lane & 15, lk = lane >> 4;
  bf16x8 Bf[2][8];
  {
    const unsigned short* base = XAT + ((size_t)(b * 9216 + hw0 + wave * 32 + lm) << 8) + lk * 8;
#pragma unroll
    for (int nt2 = 0; nt2 < 2; ++nt2)
#pragma unroll
      for (int ks = 0; ks < 8; ++ks)
        Bf[nt2][ks] = *(const bf16x8*)(base + nt2 * 16 * 256 + ks * 32);
  }
  f32x4 Y[16][2];
#pragma unroll
  for (int i = 0; i < 16; ++i) { Y[i][0] = (f32x4){0,0,0,0}; Y[i][1] = (f32x4){0,0,0,0}; }

  const uint4* g1p = (const uint4*)W1P;
  const uint4* g2p = (const uint4*)W2P;
  for (int c = 0; c < 32; ++c) {
    __syncthreads();
#pragma unroll
    for (int i = 0; i < 4; ++i) {
      int o = i * 256 + t;
      w1c4[o] = g1p[c * 1024 + o];
      w2c4[o] = g2p[c * 1024 + o];
    }
    __syncthreads();
    f32x4 Hc[2][2];
#pragma unroll
    for (int i = 0; i < 2; ++i) { Hc[i][0] = (f32x4){0,0,0,0}; Hc[i][1] = (f32x4){0,0,0,0}; }
#pragma unroll
    for (int ks = 0; ks < 8; ++ks) {
      bf16x8 a0 = *(const bf16x8*)&w1c[(ks * 64 + lane) * 8];
      bf16x8 a1 = *(const bf16x8*)&w1c[((8 + ks) * 64 + lane) * 8];
      Hc[0][0] = __builtin_amdgcn_mfma_f32_16x16x32_bf16(a0, Bf[0][ks], Hc[0][0], 0, 0, 0);
      Hc[0][1] = __builtin_amdgcn_mfma_f32_16x16x32_bf16(a0, Bf[1][ks], Hc[0][1], 0, 0, 0);
      Hc[1][0] = __builtin_amdgcn_mfma_f32_16x16x32_bf16(a1, Bf[0][ks], Hc[1][0], 0, 0, 0);
      Hc[1][1] = __builtin_amdgcn_mfma_f32_16x16x32_bf16(a1, Bf[1][ks], Hc[1][1], 0, 0, 0);
    }
#pragma unroll
    for (int mbl = 0; mbl < 2; ++mbl)
#pragma unroll
      for (int nt2 = 0; nt2 < 2; ++nt2)
#pragma unroll
        for (int r = 0; r < 4; r += 2) {
          int h = c * 32 + mbl * 16 + lk * 4 + r;
          float v0 = geluf(Hc[mbl][nt2][r]     + b1s[h]);
          float v1 = geluf(Hc[mbl][nt2][r + 1] + b1s[h + 1]);
          unsigned u = (unsigned)f2b(v0) | ((unsigned)f2b(v1) << 16);
          *(unsigned*)&hs[wave * 32 + nt2 * 16 + lm][mbl * 16 + lk * 4 + r] = u;
        }
    bf16x8 h0 = *(const bf16x8*)&hs[wave * 32 + lm][lk * 8];
    bf16x8 h1 = *(const bf16x8*)&hs[wave * 32 + 16 + lm][lk * 8];
#pragma unroll
    for (int mb = 0; mb < 16; ++mb) {
      bf16x8 a = *(const bf16x8*)&w2c[(mb * 64 + lane) * 8];
      Y[mb][0] = __builtin_amdgcn_mfma_f32_16x16x32_bf16(a, h0, Y[mb][0], 0, 0, 0);
      Y[mb][1] = __builtin_amdgcn_mfma_f32_16x16x32_bf16(a, h1, Y[mb][1], 0, 0, 0);
    }
  }
#pragma unroll
  for (int mb = 0; mb < 16; ++mb)
#pragma unroll
    for (int nt2 = 0; nt2 < 2; ++nt2)
#pragma unroll
      for (int r = 0; r < 4; ++r) {
        int m = mb * 16 + lk * 4 + r;
        size_t o = (size_t)(b * 256 + m) * 9216 + hw0 + wave * 32 + nt2 * 16 + lm;
        out[o] = Y[mb][nt2][r] + nbs[m] + xin[o];
      }
}

extern "C" void kernel_launch(void* const* d_in, const int* in_sizes, int n_in,
                              void* d_out, int out_size, void* d_ws, size_t ws_size,
                              hipStream_t stream) {
  const float* x        = (const float*)d_in[0];
  const float* pa_w1    = (const float*)d_in[1];
  const float* pa_bn_g  = (const float*)d_in[2];
  const float* pa_bn_b  = (const float*)d_in[3];
  const float* pa_w2    = (const float*)d_in[4];
  const float* fuse1_w  = (const float*)d_in[5];
  const float* la_w     = (const float*)d_in[6];
  const float* la_bn_g  = (const float*)d_in[7];
  const float* la_bn_b  = (const float*)d_in[8];
  const float* h1_w     = (const float*)d_in[9];
  const float* v1_w     = (const float*)d_in[10];
  const float* h2_w     = (const float*)d_in[11];
  const float* v2_w     = (const float*)d_in[12];
  const float* mra_bn_g = (const float*)d_in[13];
  const float* mra_bn_b = (const float*)d_in[14];
  const float* fuse2_w  = (const float*)d_in[15];
  const float* g_p1_w   = (const float*)d_in[16];
  const float* g_p1_b   = (const float*)d_in[17];
  const float* g_c0_w   = (const float*)d_in[18];
  const float* g_c0_b   = (const float*)d_in[19];
  const float* g_cs_w   = (const float*)d_in[20];
  const float* g_cs_b   = (const float*)d_in[21];
  const float* g_c1_w   = (const float*)d_in[22];
  const float* g_c1_b   = (const float*)d_in[23];
  const float* g_c2_w   = (const float*)d_in[24];
  const float* g_c2_b   = (const float*)d_in[25];
  const float* g_sq_w   = (const float*)d_in[26];
  const float* g_sq_b   = (const float*)d_in[27];
  const float* g_cv_w   = (const float*)d_in[28];
  const float* g_cv_b   = (const float*)d_in[29];
  const float* g_p2_w   = (const float*)d_in[30];
  const float* g_p2_b   = (const float*)d_in[31];
  const float* n4_g     = (const float*)d_in[32];
  const float* n4_b     = (const float*)d_in[33];
  const float* mlp_w1   = (const float*)d_in[34];
  const float* mlp_bn_g = (const float*)d_in[35];
  const float* mlp_bn_b = (const float*)d_in[36];
  const float* mlp_w2   = (const float*)d_in[37];
  const float* n1_g     = (const float*)d_in[38];
  const float* n1_b     = (const float*)d_in[39];

  // ---- aliased workspace: 44,236,800 floats = 176.9 MB ----
  float* ws = (float*)d_ws;
  bf16*  XA = (bf16*)ws;                    // (16,256,96,96) bf16 = 18,874,368 f-slots
  float* P  = ws + 18874368;                // 9,437,184 f
  float* Q  = ws + 28311552;                // 9,437,184 f
  float* R  = ws + 37748736;                // 6,225,920 f
  float* T  = R;
  float* D  = R + 1048576;
  float* E  = R + 2097152;
  float* F  = R + 4161536;
  float* C48 = P;
  int*   IDX = (int*)(P + 2359296);
  float* G   = P + 4718592;
  float* H2  = P + 7077888;
  float* I2  = Q;
  float* M   = Q + 2359296;
  float* XM  = Q + 4718592;
  float* N2  = Q + 7077888;
  float* J   = R;
  float* K2  = R + 1179648;
  float* L   = R + 2359296;
  float* AGG = R + 3538944;
  float* SG  = R + 3612672;
  unsigned short* XAT = (unsigned short*)P;
  unsigned short* W1P = (unsigned short*)(ws + 43974656);
  unsigned short* W2P = (unsigned short*)(ws + 43974656 + 131072);

  // Early bf16 frag packs: live in R head (T slot), dead before k_blur writes T.
  unsigned short* W1PA = (unsigned short*)R;   // 16384 sh
  unsigned short* W2PA = W1PA + 16384;         // 16384 sh
  unsigned short* WLAP = W1PA + 32768;         // 36864 sh
  unsigned short* F1P  = W1PA + 69632;         // 8192 sh (ends 77824 sh = 38912 f < 1048576)
  // GA-phase packs: R tail (after SG end 3686400), written post-MRA, inside E's dead zone.
  unsigned short* GWp = (unsigned short*)(R + 3686400);
  unsigned short* F2P = GWp;                   // 8192
  unsigned short* P1P = GWp + 8192;            // 4096
  unsigned short* C1P = GWp + 12288;           // 2048
  unsigned short* C2P = GWp + 14336;           // 2048
  unsigned short* CVP = GWp + 16384;           // 2048
  unsigned short* P2P = GWp + 18432;           // 4096 (ends 22528 sh = 11264 f)

  // Prep
  k_prep<<<1024, 256, 0, stream>>>(mlp_w1, mlp_bn_g, mlp_w2, n1_g, W1P, W2P);
  k_wprep<<<304, 256, 0, stream>>>(pa_w1, pa_bn_g, pa_w2, la_w, la_bn_g, fuse1_w,
                                   W1PA, W2PA, WLAP, F1P);
  // Branch 1 (PA): MFMA chained GEMMs
  k_pa<<<1152, 256, 0, stream>>>(x, W1PA, pa_bn_b, W2PA, P, XA);
  // Branch 2: fuse1 (MFMA) -> Q; la (MFMA implicit GEMM) -> xa ch 64..127
  k_cg<4, 2, 2><<<1152, 256, 0, stream>>>(P, x, 64, F1P, (const float*)nullptr, 0, Q, 9216);
  k_la<<<1536, 384, 0, stream>>>(Q, WLAP, la_bn_b, XA);
  // Branch 3 (MRA)
  k_maxpool3<<<36864, 256, 0, stream>>>(x, P);
  k_blur<<<4096, 256, 0, stream>>>(P, T);
  k_dw<<<4096, 256, 0, stream>>>(T, h1_w, (const float*)nullptr, D, 32, 32, 7, 3, 3, 1, 1, 0);
  k_dw<<<4096, 256, 0, stream>>>(T, v1_w, (const float*)nullptr, D, 32, 32, 3, 7, 1, 3, 1, 1);
  k_htrans<<<8064, 256, 0, stream>>>(T, E);
  k_dw<<<8064, 256, 0, stream>>>(E, h2_w, (const float*)nullptr, F, 32, 63, 7, 3, 3, 1, 1, 0);
  k_invh_add<<<4096, 256, 0, stream>>>(F, D);
  k_vtrans<<<8064, 256, 0, stream>>>(T, E);
  k_dw<<<8064, 256, 0, stream>>>(E, v2_w, (const float*)nullptr, F, 63, 32, 3, 7, 1, 3, 1, 0);
  k_invv_add<<<4096, 256, 0, stream>>>(F, D);
  k_gate<<<36864, 256, 0, stream>>>(D, x, mra_bn_g, mra_bn_b, P, XA);
  // Branch 4 (GA): all 1x1s via MFMA
  k_wprep2<<<88, 256, 0, stream>>>(fuse2_w, g_p1_w, g_c1_w, g_c2_w, g_cv_w, g_p2_w,
                                   F2P, P1P, C1P, C2P, CVP, P2P);
  k_cg<4, 2, 2><<<1152, 256, 0, stream>>>(P, x, 192, F2P, (const float*)nullptr, 0, Q, 9216);
  k_pool2<<<9216, 256, 0, stream>>>(Q, C48, IDX);
  k_cg<4, 2, 0><<<288, 256, 0, stream>>>(C48, (const float*)nullptr, 0, P1P, g_p1_b, 1, G, 2304);
  k_dw<<<9216, 256, 0, stream>>>(G, g_c0_w, g_c0_b, H2, 48, 48, 5, 5, 2, 2, 1, 0);
  k_dw<<<9216, 256, 0, stream>>>(H2, g_cs_w, g_cs_b, I2, 48, 48, 7, 7, 9, 9, 3, 0);
  k_cg<2, 2, 0><<<288, 256, 0, stream>>>(H2, (const float*)nullptr, 0, C1P, g_c1_b, 0, J, 2304);
  k_cg<2, 2, 0><<<288, 256, 0, stream>>>(I2, (const float*)nullptr, 0, C2P, g_c2_b, 0, K2, 2304);
  k_agg<<<144, 256, 0, stream>>>(J, K2, AGG);
  k_sq<<<288, 256, 0, stream>>>(AGG, g_sq_w, g_sq_b, SG);
  k_mix<<<4608, 256, 0, stream>>>(J, K2, SG, L);
  k_cg<4, 1, 0><<<288, 256, 0, stream>>>(L, (const float*)nullptr, 0, CVP, g_cv_b, 0, M, 2304);
  k_mul<<<9216, 256, 0, stream>>>(G, M, XM);
  k_cg<4, 2, 0><<<288, 256, 0, stream>>>(XM, (const float*)nullptr, 0, P2P, g_p2_b, 0, N2, 2304);
  k_unpool<<<36864, 256, 0, stream>>>(N2, IDX, x, n4_g, n4_b, XA);
  // Transpose xa -> pixel-major
  k_tr<<<9216, 256, 0, stream>>>((const unsigned short*)XA, XAT);
  // MLP + residual
  k_mlp_mfma<<<1152, 256, 0, stream>>>(XAT, W1P, mlp_bn_b, W2P, n1_b, x, (float*)d_out);
}